// Round 3
// baseline (99.057 us; speedup 1.0000x reference)
//
#include <hip/hip_runtime.h>
#include <math.h>

#define NP 16384   // spatial positions = 32*32*16
#define HDIM 32
#define WDIM 32
#define ZDIM 16

typedef short bf16x8 __attribute__((ext_vector_type(8)));
typedef unsigned short u16x8 __attribute__((ext_vector_type(8)));
typedef float f32x4 __attribute__((ext_vector_type(4)));

__device__ __forceinline__ unsigned short f2bf(float f) {
    unsigned int u = __float_as_uint(f);
    return (unsigned short)((u + 0x7fffu + ((u >> 16) & 1u)) >> 16);
}
__device__ __forceinline__ float bf2f(unsigned short s) {
    return __uint_as_float(((unsigned int)s) << 16);
}

// ---------------------------------------------------------------------------
// x [128][NP] f32  ->  xT hi/lo bf16 planes [NP][128]
// One thread per position p; 128 strided reads, 16B packed stores.
// ---------------------------------------------------------------------------
__global__ __launch_bounds__(256) void convert_x(
    const float* __restrict__ x, unsigned short* __restrict__ xhi,
    unsigned short* __restrict__ xlo)
{
    const int p = blockIdx.x * 256 + threadIdx.x;
    #pragma unroll
    for (int g = 0; g < 16; ++g) {
        u16x8 vh, vl;
        #pragma unroll
        for (int j = 0; j < 8; ++j) {
            const float v = x[(g * 8 + j) * NP + p];
            const unsigned short h = f2bf(v);
            vh[j] = h;
            vl[j] = f2bf(v - bf2f(h));
        }
        *(u16x8*)&xhi[p * 128 + g * 8] = vh;
        *(u16x8*)&xlo[p * 128 + g * 8] = vl;
    }
}

// ---------------------------------------------------------------------------
// W [M][128] f32 -> hi/lo bf16 planes (same layout). 8 elems/thread.
// ---------------------------------------------------------------------------
__global__ __launch_bounds__(256) void convert_w(
    const float* __restrict__ W, unsigned short* __restrict__ whi,
    unsigned short* __restrict__ wlo, int n8)
{
    const int e = blockIdx.x * 256 + threadIdx.x;
    if (e >= n8) return;
    u16x8 vh, vl;
    #pragma unroll
    for (int j = 0; j < 8; ++j) {
        const float v = W[e * 8 + j];
        const unsigned short h = f2bf(v);
        vh[j] = h;
        vl[j] = f2bf(v - bf2f(h));
    }
    *(u16x8*)&whi[e * 8] = vh;
    *(u16x8*)&wlo[e * 8] = vl;
}

// ---------------------------------------------------------------------------
// MFMA GEMM with bf16 hi/lo split: C[o][p] = A[o][:] . B[p][:] + bias[o]
// A planes: [M][128] bf16 (row-major). B planes: [NP][128] bf16 (transposed).
// C: f32 [M][NP].  Block = 4 waves; wave computes 16 rows x 64 cols.
// Grid: (NP/256, M/16). No LDS, K=128 entirely in registers.
// Fragment maps (16x16x32): A row=lane&15, k=(lane>>4)*8+j; B col=lane&15;
// D col=lane&15, row=(lane>>4)*4+reg  [m89-verified].
// ---------------------------------------------------------------------------
__global__ __launch_bounds__(256) void gemm_mfma_split(
    const unsigned short* __restrict__ Ahi, const unsigned short* __restrict__ Alo,
    const unsigned short* __restrict__ Bhi, const unsigned short* __restrict__ Blo,
    const float* __restrict__ bias, float* __restrict__ C)
{
    const int lane = threadIdx.x & 63;
    const int wv   = threadIdx.x >> 6;
    const int row0 = blockIdx.y * 16;
    const int colbase = blockIdx.x * 256 + wv * 64;
    const int rlane = lane & 15;
    const int kgrp  = lane >> 4;

    // A fragments (reused for all 4 col-subtiles)
    bf16x8 ah[4], al[4];
    {
        const int abase = (row0 + rlane) * 128 + kgrp * 8;
        #pragma unroll
        for (int kb = 0; kb < 4; ++kb) {
            ah[kb] = *(const bf16x8*)(Ahi + abase + kb * 32);
            al[kb] = *(const bf16x8*)(Alo + abase + kb * 32);
        }
    }
    // bias for this lane's 4 output rows
    float b4[4];
    #pragma unroll
    for (int r = 0; r < 4; ++r) b4[r] = bias[row0 + kgrp * 4 + r];

    #pragma unroll
    for (int ct = 0; ct < 4; ++ct) {
        const int p = colbase + ct * 16 + rlane;
        f32x4 acc = {0.f, 0.f, 0.f, 0.f};
        #pragma unroll
        for (int kb = 0; kb < 4; ++kb) {
            const int boff = p * 128 + kb * 32 + kgrp * 8;
            const bf16x8 bh = *(const bf16x8*)(Bhi + boff);
            const bf16x8 bl = *(const bf16x8*)(Blo + boff);
            acc = __builtin_amdgcn_mfma_f32_16x16x32_bf16(ah[kb], bh, acc, 0, 0, 0);
            acc = __builtin_amdgcn_mfma_f32_16x16x32_bf16(ah[kb], bl, acc, 0, 0, 0);
            acc = __builtin_amdgcn_mfma_f32_16x16x32_bf16(al[kb], bh, acc, 0, 0, 0);
        }
        #pragma unroll
        for (int r = 0; r < 4; ++r)
            C[(row0 + kgrp * 4 + r) * NP + p] = acc[r] + b4[r];
    }
}

// ---------------------------------------------------------------------------
// 3D neighborhood attention, k=3x3x3, NATTEN clamped windows.
// qkv f32 [384][NP]; writes attnT hi/lo bf16 planes [NP][128].
// 4 lanes per (head,pos): lane = z + 16*chunk, chunk owns 8 channels.
// Grid: (256, 4), 256 threads.
// ---------------------------------------------------------------------------
__global__ __launch_bounds__(256) void natten3d_v3(
    const float* __restrict__ qkv, const float* __restrict__ rpb,
    unsigned short* __restrict__ athi, unsigned short* __restrict__ atlo)
{
    const int tid  = threadIdx.x;
    const int head = blockIdx.y;
    const int lane = tid & 63;
    const int wave = tid >> 6;
    const int z     = lane & 15;
    const int chunk = lane >> 4;
    const int col   = blockIdx.x * 4 + wave;
    const int h = col >> 5;
    const int w = col & 31;
    const int p = col * 16 + z;

    __shared__ float bias_s[125];
    if (tid < 125) bias_s[tid] = rpb[head * 125 + tid];
    __syncthreads();

    const float scale = 0.17677669529663687f;  // 32^-0.5
    const float* __restrict__ qb = qkv + (head * 32 + chunk * 8) * NP;
    const float* __restrict__ kb = qkv + (128 + head * 32 + chunk * 8) * NP;
    const float* __restrict__ vb = qkv + (256 + head * 32 + chunk * 8) * NP;

    float q[8];
    #pragma unroll
    for (int d = 0; d < 8; ++d) q[d] = qb[d * NP + p] * scale;

    int hs = h - 1; hs = hs < 0 ? 0 : (hs > HDIM - 3 ? HDIM - 3 : hs);
    int ws_ = w - 1; ws_ = ws_ < 0 ? 0 : (ws_ > WDIM - 3 ? WDIM - 3 : ws_);
    int zs = z - 1; zs = zs < 0 ? 0 : (zs > ZDIM - 3 ? ZDIM - 3 : zs);
    const int rh0 = hs - h + 2;
    const int rw0 = ws_ - w + 2;
    const int rz0 = zs - z + 2;

    float s[27];
    float smax = -1e30f;
    #pragma unroll
    for (int dh = 0; dh < 3; ++dh) {
        #pragma unroll
        for (int dw = 0; dw < 3; ++dw) {
            #pragma unroll
            for (int dz = 0; dz < 3; ++dz) {
                const int m = (dh * 3 + dw) * 3 + dz;
                const int pn = (hs + dh) * 512 + (ws_ + dw) * 16 + (zs + dz);
                float acc = 0.f;
                #pragma unroll
                for (int d = 0; d < 8; ++d)
                    acc = fmaf(q[d], kb[d * NP + pn], acc);
                acc += __shfl_xor(acc, 16, 64);
                acc += __shfl_xor(acc, 32, 64);
                acc += bias_s[((rh0 + dh) * 5 + (rw0 + dw)) * 5 + (rz0 + dz)];
                s[m] = acc;
                smax = fmaxf(smax, acc);
            }
        }
    }

    float ssum = 0.f;
    #pragma unroll
    for (int m = 0; m < 27; ++m) {
        s[m] = __expf(s[m] - smax);
        ssum += s[m];
    }
    const float inv = 1.f / ssum;

    float o[8];
    #pragma unroll
    for (int d = 0; d < 8; ++d) o[d] = 0.f;

    #pragma unroll
    for (int dh = 0; dh < 3; ++dh) {
        #pragma unroll
        for (int dw = 0; dw < 3; ++dw) {
            #pragma unroll
            for (int dz = 0; dz < 3; ++dz) {
                const int m = (dh * 3 + dw) * 3 + dz;
                const int pn = (hs + dh) * 512 + (ws_ + dw) * 16 + (zs + dz);
                const float pm = s[m];
                #pragma unroll
                for (int d = 0; d < 8; ++d)
                    o[d] = fmaf(pm, vb[d * NP + pn], o[d]);
            }
        }
    }

    // write transposed bf16 hi/lo: attnT[p][head*32 + chunk*8 + d]
    const int cbase = head * 32 + chunk * 8;
    u16x8 vh, vl;
    #pragma unroll
    for (int d = 0; d < 8; ++d) {
        const float val = o[d] * inv;
        const unsigned short hh = f2bf(val);
        vh[d] = hh;
        vl[d] = f2bf(val - bf2f(hh));
    }
    *(u16x8*)&athi[p * 128 + cbase] = vh;
    *(u16x8*)&atlo[p * 128 + cbase] = vl;
}

// ---------------------------------------------------------------------------
extern "C" void kernel_launch(void* const* d_in, const int* in_sizes, int n_in,
                              void* d_out, int out_size, void* d_ws, size_t ws_size,
                              hipStream_t stream)
{
    const float* x    = (const float*)d_in[0];  // (1,128,32,32,16)
    const float* Wqkv = (const float*)d_in[1];  // (384,128)
    const float* bqkv = (const float*)d_in[2];  // (384,)
    const float* rpb  = (const float*)d_in[3];  // (4,5,5,5)
    const float* Wp   = (const float*)d_in[4];  // (128,128)
    const float* bp   = (const float*)d_in[5];  // (128,)
    float* out = (float*)d_out;                 // (1,128,32,32,16)

    float* qkv = (float*)d_ws;                        // 384*NP f32 = 24 MB
    unsigned short* base = (unsigned short*)(qkv + 384 * NP);
    unsigned short* xhi  = base;                      // NP*128 each (4 MB)
    unsigned short* xlo  = base + (size_t)NP * 128;
    unsigned short* athi = base + (size_t)2 * NP * 128;
    unsigned short* atlo = base + (size_t)3 * NP * 128;
    unsigned short* wqh  = base + (size_t)4 * NP * 128;
    unsigned short* wql  = wqh + 384 * 128;
    unsigned short* wph  = wql + 384 * 128;
    unsigned short* wpl  = wph + 128 * 128;

    // input conversions
    convert_x<<<dim3(NP / 256), dim3(256), 0, stream>>>(x, xhi, xlo);
    convert_w<<<dim3(384 * 128 / 8 / 256), dim3(256), 0, stream>>>(Wqkv, wqh, wql, 384 * 128 / 8);
    convert_w<<<dim3(8), dim3(256), 0, stream>>>(Wp, wph, wpl, 128 * 128 / 8);

    // 1) QKV projection (MFMA, hi/lo split): qkv f32 [384][NP]
    gemm_mfma_split<<<dim3(NP / 256, 384 / 16), dim3(256), 0, stream>>>(
        wqh, wql, xhi, xlo, bqkv, qkv);

    // 2) neighborhood attention -> bf16 transposed hi/lo planes
    natten3d_v3<<<dim3(256, 4), dim3(256), 0, stream>>>(qkv, rpb, athi, atlo);

    // 3) output projection (MFMA, hi/lo split) -> f32 out
    gemm_mfma_split<<<dim3(NP / 256, 128 / 16), dim3(256), 0, stream>>>(
        wph, wpl, athi, atlo, bp, out);
}